// Round 8
// baseline (18.976 us; speedup 1.0000x reference)
//
#include <hip/hip_runtime.h>
#include <hip/hip_bf16.h>
#include <cstdint>
#include <cstddef>

#define IN_DIM 128
#define OUT_DIM 128
#define NB 8
#define BM 64                       // rows per block
#define BN 64                       // cols per block
#define NT 9                        // K-tiles: 8 spline (i-sliced) + 1 base(silu)
#define BUFB (64 * 256)             // one A-tile buffer: 64 rows x 256B = 16 KiB
#define PANE_F (64 * 33)            // reduction pane floats
#define SMEM_BYTES (6 * PANE_F * 4) // 50688 > 2*BUFB (32768)

using bf16 = __hip_bfloat16;
typedef __attribute__((ext_vector_type(8))) short short8;   // 8 bf16
typedef __attribute__((ext_vector_type(4))) float f32x4;

// ---------------------------------------------------------------------------
// Uniform cubic B-spline: grid knots g0..g11, spacing h. x in [g_j,g_{j+1}):
// nonzero basis m = j-3..j (clipped to [0,7]) with standard cubic weights.
// ---------------------------------------------------------------------------
__device__ __forceinline__ void basis_weights(float xv, float g0, float inv_h,
                                              int& j, float& w0, float& w1,
                                              float& w2, float& w3) {
    float t = (xv - g0) * inv_h;
    float jf = floorf(t);
    j = (int)jf;
    float u = t - jf;
    float um = 1.f - u;
    float u2 = u * u, u3 = u2 * u;
    w0 = um * um * um * (1.f / 6.f);
    w1 = (3.f * u3 - 6.f * u2 + 4.f) * (1.f / 6.f);
    w2 = (-3.f * u3 + 3.f * u2 + 3.f * u + 1.f) * (1.f / 6.f);
    w3 = u3 * (1.f / 6.f);
}

__device__ __forceinline__ unsigned short to_bf16_bits(float v) {
    bf16 h = __float2bfloat16(v);
    return *(unsigned short*)&h;
}

__device__ __forceinline__ short8 pack8(const float4& a, const float4& b) {
    short8 p;
    p[0] = (short)to_bf16_bits(a.x); p[1] = (short)to_bf16_bits(a.y);
    p[2] = (short)to_bf16_bits(a.z); p[3] = (short)to_bf16_bits(a.w);
    p[4] = (short)to_bf16_bits(b.x); p[5] = (short)to_bf16_bits(b.y);
    p[6] = (short)to_bf16_bits(b.z); p[7] = (short)to_bf16_bits(b.w);
    return p;
}

// ---------------------------------------------------------------------------
// Single fused kernel. 64x64 output tile/block, grid = (B/64)*2 = 256.
// K order: tile t<8 covers i in [16t,16t+16) x 8 basis fns; tile 8 = silu*W.
// 512 thr = 8 waves = (g: 4-way ksplit, one MFMA-k-step each) x (w: 2 col-
// groups of 32). Per tile: features for tile t+1 computed into the other
// 16 KiB LDS buffer (dbuf, 1 barrier/iter); B-frags straight from C/W f32
// (each element exactly once per block -> 74 MB L2 total), depth-1 register
// prefetch; A via 4x ds_read_b128 (chunk^row&7 swizzle, bank-uniform);
// 8 MFMA/wave/tile. Epilogue: 4-way ksplit reduce via LDS panes.
// ---------------------------------------------------------------------------
__global__ __launch_bounds__(512)
void k_kan(const float* __restrict__ x, const float* __restrict__ grid,
           const float* __restrict__ C, const float* __restrict__ W,
           const float* __restrict__ scale, float* __restrict__ out) {
    __shared__ __align__(16) char smem[SMEM_BYTES];

    const int tid = threadIdx.x;
    const int lane = tid & 63;
    const int wave = tid >> 6;
    const int g = wave >> 1;           // 0..3: MFMA-k-step within tile
    const int w = wave & 1;            // 0..1: col-group of 32
    const int m0 = (blockIdx.x >> 1) * BM;
    const int n0 = (blockIdx.x & 1) * BN;
    const int r0 = lane & 15;
    const int ksub = lane >> 4;        // 0..3

    int ocol[2];
    ocol[0] = n0 + w * 32 + r0;
    ocol[1] = n0 + w * 32 + 16 + r0;

    const float g0v = grid[0];
    const float inv_h = 1.f / (grid[4] - grid[3]);

    // feature threads: row = tid>>3 (0..63), ih = tid&7 (2 chunks each)
    const int frow = tid >> 3;
    const int fih = tid & 7;
    char* const Arow_base = smem + frow * 256;

    // ---- B-fragment loads straight from C / W (f32) ----
    float4 cb[2][2], pf[2][2];         // [n][half]
    auto load_spline = [&](int t, float4 (&dst)[2][2]) {
        int i = t * 16 + g * 4 + ksub;
#pragma unroll
        for (int n = 0; n < 2; ++n) {
            const float* src = C + ((size_t)i * 128 + ocol[n]) * 8;
            dst[n][0] = *(const float4*)src;
            dst[n][1] = *(const float4*)(src + 4);
        }
    };
    auto load_base = [&](float4 (&dst)[2][2]) {
        int ibase = (g * 4 + ksub) * 8;
#pragma unroll
        for (int n = 0; n < 2; ++n) {
            float v[8];
#pragma unroll
            for (int e = 0; e < 8; ++e)
                v[e] = W[(size_t)(ibase + e) * 128 + ocol[n]];
            dst[n][0] = make_float4(v[0], v[1], v[2], v[3]);
            dst[n][1] = make_float4(v[4], v[5], v[6], v[7]);
        }
    };

    // ---- per-tile feature compute into LDS buffer ----
    auto feat_spline = [&](int t, int buf) {
        float2 xv = *(const float2*)(x + (size_t)(m0 + frow) * IN_DIM + t * 16 + fih * 2);
        float xe[2] = {xv.x, xv.y};
#pragma unroll
        for (int e = 0; e < 2; ++e) {
            int j; float w0, w1, w2, w3;
            basis_weights(xe[e], g0v, inv_h, j, w0, w1, w2, w3);
            bool inr = (j >= 0) && (j < 11);
            short8 bas;
#pragma unroll
            for (int m = 0; m < 8; ++m) {
                int k2 = m - (j - 3);
                float val = 0.f;
                if (inr && k2 >= 0 && k2 < 4)
                    val = (k2 == 0) ? w0 : (k2 == 1) ? w1 : (k2 == 2) ? w2 : w3;
                bas[m] = (short)to_bf16_bits(val);
            }
            int ci = fih * 2 + e;
            *(short8*)(Arow_base + buf * BUFB + ((ci ^ (frow & 7)) << 4)) = bas;
        }
    };
    auto feat_base = [&](int buf) {
#pragma unroll
        for (int e = 0; e < 2; ++e) {
            int ci = fih * 2 + e;                   // i = ci*8 .. +7
            const float* xr = x + (size_t)(m0 + frow) * IN_DIM + ci * 8;
            float4 xa = *(const float4*)xr;
            float4 xb = *(const float4*)(xr + 4);
            float xv[8] = {xa.x, xa.y, xa.z, xa.w, xb.x, xb.y, xb.z, xb.w};
            short8 sil;
#pragma unroll
            for (int q = 0; q < 8; ++q)
                sil[q] = (short)to_bf16_bits(xv[q] / (1.f + __expf(-xv[q])));
            *(short8*)(Arow_base + buf * BUFB + ((ci ^ (frow & 7)) << 4)) = sil;
        }
    };

    // ---- prologue: tile-0 B loads + tile-0 features ----
    load_spline(0, cb);
    feat_spline(0, 0);
    __syncthreads();

    f32x4 acc[4][2];
#pragma unroll
    for (int rg = 0; rg < 4; ++rg)
#pragma unroll
        for (int n = 0; n < 2; ++n) acc[rg][n] = 0.f;

    int cur = 0;
#pragma unroll
    for (int t = 0; t < NT; ++t) {
        if (t + 1 < 8)        load_spline(t + 1, pf);
        else if (t + 1 == 8)  load_base(pf);

        if (t + 1 < 8)        feat_spline(t + 1, cur ^ 1);
        else if (t + 1 == 8)  feat_base(cur ^ 1);

        short8 b[2];
#pragma unroll
        for (int n = 0; n < 2; ++n)
            b[n] = pack8(cb[n][0], cb[n][1]);

        const int c = g * 4 + ksub;                 // within-tile A chunk
        short8 a[4];
#pragma unroll
        for (int rg = 0; rg < 4; ++rg) {
            int row = rg * 16 + r0;
            int cs = c ^ (row & 7);
            a[rg] = *(const short8*)(smem + cur * BUFB + row * 256 + cs * 16);
        }
#pragma unroll
        for (int rg = 0; rg < 4; ++rg)
#pragma unroll
            for (int n = 0; n < 2; ++n)
                acc[rg][n] = __builtin_amdgcn_mfma_f32_16x16x32_bf16(
                    a[rg], b[n], acc[rg][n], 0, 0, 0);

        if (t + 1 < NT) {
#pragma unroll
            for (int n = 0; n < 2; ++n)
#pragma unroll
                for (int h = 0; h < 2; ++h)
                    cb[n][h] = pf[n][h];
        }
        __syncthreads();
        cur ^= 1;
    }

    // ---- 4-way ksplit reduction via LDS panes (overlaying buffers) ----
    float* pane = (float*)smem;        // 6 panes of [64][33] f32
    if (g > 0) {
        const int pbase = (w * 3 + (g - 1)) * PANE_F;
#pragma unroll
        for (int rg = 0; rg < 4; ++rg)
#pragma unroll
            for (int n = 0; n < 2; ++n)
#pragma unroll
                for (int q = 0; q < 4; ++q) {
                    int row = rg * 16 + ksub * 4 + q;
                    pane[pbase + row * 33 + n * 16 + r0] = acc[rg][n][q];
                }
    }
    __syncthreads();
    if (g == 0) {
        float s = scale[0];
        const int pb0 = (w * 3 + 0) * PANE_F;
        const int pb1 = (w * 3 + 1) * PANE_F;
        const int pb2 = (w * 3 + 2) * PANE_F;
#pragma unroll
        for (int rg = 0; rg < 4; ++rg)
#pragma unroll
            for (int n = 0; n < 2; ++n)
#pragma unroll
                for (int q = 0; q < 4; ++q) {
                    int row = rg * 16 + ksub * 4 + q;
                    int po = row * 33 + n * 16 + r0;
                    float v = acc[rg][n][q] + pane[pb0 + po] + pane[pb1 + po] + pane[pb2 + po];
                    out[(size_t)(m0 + row) * OUT_DIM + n0 + w * 32 + n * 16 + r0] = v * s;
                }
    }
}

// ---------------------------------------------------------------------------
// Fallback: fully fused f32, correct but slow (only if B % 64 != 0).
// ---------------------------------------------------------------------------
__global__ void k_naive(const float* __restrict__ x, const float* __restrict__ grid,
                        const float* __restrict__ C, const float* __restrict__ W,
                        const float* __restrict__ scale, float* __restrict__ out) {
    __shared__ float sS[128];
    __shared__ float sB[128][8];
    int b = blockIdx.x, t = threadIdx.x;   // 128 threads
    float xv = x[(size_t)b * IN_DIM + t];
    float g0 = grid[0];
    float inv_h = 1.f / (grid[4] - grid[3]);
    sS[t] = xv / (1.f + __expf(-xv));
    int j; float w0, w1, w2, w3;
    basis_weights(xv, g0, inv_h, j, w0, w1, w2, w3);
    bool inrange = (j >= 0) && (j < 11);
#pragma unroll
    for (int m = 0; m < 8; ++m) {
        int k2 = m - (j - 3);
        float val = 0.f;
        if (inrange && k2 >= 0 && k2 < 4)
            val = (k2 == 0) ? w0 : (k2 == 1) ? w1 : (k2 == 2) ? w2 : w3;
        sB[t][m] = val;
    }
    __syncthreads();
    float acc = 0.f;
    for (int i = 0; i < IN_DIM; ++i) {
        acc += sS[i] * W[(size_t)i * OUT_DIM + t];
        const float* c = C + ((size_t)i * OUT_DIM + t) * NB;
#pragma unroll
        for (int m = 0; m < 8; ++m) acc += sB[i][m] * c[m];
    }
    out[(size_t)b * OUT_DIM + t] = acc * scale[0];
}

// ---------------------------------------------------------------------------
extern "C" void kernel_launch(void* const* d_in, const int* in_sizes, int n_in,
                              void* d_out, int out_size, void* d_ws, size_t ws_size,
                              hipStream_t stream) {
    const float* x     = (const float*)d_in[0];
    const float* grid  = (const float*)d_in[1];
    const float* C     = (const float*)d_in[2];
    const float* W     = (const float*)d_in[3];
    const float* scale = (const float*)d_in[4];
    float* out = (float*)d_out;

    int B = in_sizes[0] / IN_DIM;   // 8192

    if ((B % BM) == 0) {
        k_kan<<<(B / BM) * 2, 512, 0, stream>>>(x, grid, C, W, scale, out);
    } else {
        k_naive<<<B, 128, 0, stream>>>(x, grid, C, W, scale, out);
    }
}

// Round 9
// 16.407 us; speedup vs baseline: 1.1566x; 1.1566x over previous
//
#include <hip/hip_runtime.h>
#include <hip/hip_bf16.h>
#include <cstdint>
#include <cstddef>

#define IN_DIM 128
#define OUT_DIM 128
#define NB 8
#define BM 32
#define NT 9                        // 9 K-tiles of 128; K order: spline k=i*8+m, base k=1024+i
#define A_ROW_BYTES 2304            // 1152 bf16 = 144 x 16B chunks
#define A_BYTES (BM * A_ROW_BYTES)  // 73728

using bf16 = __hip_bfloat16;
typedef __attribute__((ext_vector_type(8))) short short8;   // 8 bf16
typedef __attribute__((ext_vector_type(4))) float f32x4;

// ---------------------------------------------------------------------------
// Uniform cubic B-spline: grid knots g0..g11, spacing h. x in [g_j,g_{j+1}):
// nonzero basis m = j-3..j (clipped to [0,7]) with standard cubic weights.
// ---------------------------------------------------------------------------
__device__ __forceinline__ void basis_weights(float xv, float g0, float inv_h,
                                              int& j, float& w0, float& w1,
                                              float& w2, float& w3) {
    float t = (xv - g0) * inv_h;
    float jf = floorf(t);
    j = (int)jf;
    float u = t - jf;
    float um = 1.f - u;
    float u2 = u * u, u3 = u2 * u;
    w0 = um * um * um * (1.f / 6.f);
    w1 = (3.f * u3 - 6.f * u2 + 4.f) * (1.f / 6.f);
    w2 = (-3.f * u3 + 3.f * u2 + 3.f * u + 1.f) * (1.f / 6.f);
    w3 = u3 * (1.f / 6.f);
}

__device__ __forceinline__ unsigned short to_bf16_bits(float v) {
    bf16 h = __float2bfloat16(v);
    return *(unsigned short*)&h;
}

__device__ __forceinline__ short8 pack8(const float4& a, const float4& b) {
    short8 p;
    p[0] = (short)to_bf16_bits(a.x); p[1] = (short)to_bf16_bits(a.y);
    p[2] = (short)to_bf16_bits(a.z); p[3] = (short)to_bf16_bits(a.w);
    p[4] = (short)to_bf16_bits(b.x); p[5] = (short)to_bf16_bits(b.y);
    p[6] = (short)to_bf16_bits(b.z); p[7] = (short)to_bf16_bits(b.w);
    return p;
}

// ---------------------------------------------------------------------------
// Single fused kernel, barrier-free K-loop, depth-2 B prefetch.
// Per block (BM=32 rows, 512 thr = 8 waves = (g:2 ksplit) x (w:4 col-groups)):
//   1. issue tile-0/1 B-frag loads; compute 32x1152 bf16 feature tile into
//      persistent XOR-swizzled LDS A; one barrier.
//   2. fully-unrolled K-loop: B-fragments loaded straight from C (f32,
//      coalesced 32B/lane) into a 2-slot register pipeline (loads issued 2
//      tiles ahead; slot index folds to a constant under full unroll),
//      cvt to bf16 in-reg, A-frags via ds_read_b128, 8 MFMAs/wave/tile.
//      No syncthreads in the loop.
//   3. ks-split reduction via LDS panes, store.
// Per-block global traffic: C+W read exactly once (576 KB) — minimal at BM=32.
// ---------------------------------------------------------------------------
__global__ __launch_bounds__(512)
void k_kan(const float* __restrict__ x, const float* __restrict__ grid,
           const float* __restrict__ C, const float* __restrict__ W,
           const float* __restrict__ scale, float* __restrict__ out) {
    __shared__ __align__(16) char smem[A_BYTES];   // 73.7 KiB

    const int tid = threadIdx.x;
    const int lane = tid & 63;
    const int m0 = blockIdx.x * BM;
    const int w = (tid >> 6) & 3;      // col-group: cols w*32..+31
    const int g = tid >> 8;            // k-split half
    const int r0 = lane & 15;
    const int ksub = lane >> 4;

    int ocol[2];                       // frag columns
    ocol[0] = w * 32 + r0;
    ocol[1] = w * 32 + 16 + r0;

    float4 buf[2][2][2][2];            // [slot][k2][n][half] f32 B pipeline

    auto load_spline = [&](int t, float4 (&dst)[2][2][2]) {
#pragma unroll
        for (int k2 = 0; k2 < 2; ++k2) {
            int i = t * 16 + (2 * g + k2) * 4 + ksub;
#pragma unroll
            for (int n = 0; n < 2; ++n) {
                const float* src = C + ((size_t)i * 128 + ocol[n]) * 8;
                dst[k2][n][0] = *(const float4*)src;
                dst[k2][n][1] = *(const float4*)(src + 4);
            }
        }
    };
    auto load_base = [&](float4 (&dst)[2][2][2]) {
#pragma unroll
        for (int k2 = 0; k2 < 2; ++k2) {
            int ibase = (2 * g + k2) * 32 + ksub * 8;
#pragma unroll
            for (int n = 0; n < 2; ++n) {
                float v[8];
#pragma unroll
                for (int e = 0; e < 8; ++e)
                    v[e] = W[(size_t)(ibase + e) * 128 + ocol[n]];
                dst[k2][n][0] = make_float4(v[0], v[1], v[2], v[3]);
                dst[k2][n][1] = make_float4(v[4], v[5], v[6], v[7]);
            }
        }
    };

    // two tiles in flight before the feature prologue
    load_spline(0, buf[0]);
    load_spline(1, buf[1]);

    // ---- features into persistent A: thread (row=tid>>4, ip=tid&15) ----
    {
        int row = tid >> 4, ip = tid & 15;
        const float* xr = x + (size_t)(m0 + row) * IN_DIM + ip * 8;
        float4 xa = *(const float4*)xr;
        float4 xb = *(const float4*)(xr + 4);
        float xv[8] = {xa.x, xa.y, xa.z, xa.w, xb.x, xb.y, xb.z, xb.w};
        float g0 = grid[0];
        float inv_h = 1.f / (grid[4] - grid[3]);
        char* Arow = smem + row * A_ROW_BYTES;
        short8 sil;
#pragma unroll
        for (int e = 0; e < 8; ++e) {
            float v = xv[e];
            sil[e] = (short)to_bf16_bits(v / (1.f + __expf(-v)));
            int j; float w0, w1, w2, w3;
            basis_weights(v, g0, inv_h, j, w0, w1, w2, w3);
            bool inr = (j >= 0) && (j < 11);
            short8 bas;
#pragma unroll
            for (int m = 0; m < 8; ++m) {
                int k2 = m - (j - 3);
                float val = 0.f;
                if (inr && k2 >= 0 && k2 < 4)
                    val = (k2 == 0) ? w0 : (k2 == 1) ? w1 : (k2 == 2) ? w2 : w3;
                bas[m] = (short)to_bf16_bits(val);
            }
            int chunk = (ip * 8 + e) ^ (row & 7);   // chunk i holds k=i*8+m
            *(short8*)(Arow + chunk * 16) = bas;
        }
        int chunk = (128 + ip) ^ (row & 7);         // base: silu[i0..i0+7]
        *(short8*)(Arow + chunk * 16) = sil;
    }
    __syncthreads();   // the only barrier before the epilogue

    f32x4 acc[2][2];
#pragma unroll
    for (int rg = 0; rg < 2; ++rg)
#pragma unroll
        for (int n = 0; n < 2; ++n) acc[rg][n] = 0.f;

    // ---- barrier-free K loop; slot = t&1 is compile-time under unroll ----
#pragma unroll
    for (int t = 0; t < NT; ++t) {
        const int slot = t & 1;

        // consume the staged f32 into bf16 frags, freeing the slot
        short8 b[2][2];
#pragma unroll
        for (int k2 = 0; k2 < 2; ++k2)
#pragma unroll
            for (int n = 0; n < 2; ++n)
                b[k2][n] = pack8(buf[slot][k2][n][0], buf[slot][k2][n][1]);

        // refill the slot with tile t+2 (lands ~2 iterations later)
        if (t + 2 < 8)        load_spline(t + 2, buf[slot]);
        else if (t + 2 == 8)  load_base(buf[slot]);

        short8 a[2][2];
#pragma unroll
        for (int rg = 0; rg < 2; ++rg) {
            int row = rg * 16 + r0;
#pragma unroll
            for (int k2 = 0; k2 < 2; ++k2) {
                int c = t * 16 + (2 * g + k2) * 4 + ksub;
                int cs = c ^ (row & 7);
                a[rg][k2] = *(const short8*)(smem + row * A_ROW_BYTES + cs * 16);
            }
        }
#pragma unroll
        for (int k2 = 0; k2 < 2; ++k2)
#pragma unroll
            for (int rg = 0; rg < 2; ++rg)
#pragma unroll
                for (int n = 0; n < 2; ++n)
                    acc[rg][n] = __builtin_amdgcn_mfma_f32_16x16x32_bf16(
                        a[rg][k2], b[k2][n], acc[rg][n], 0, 0, 0);
    }

    // ---- ks-split reduction via LDS panes (A region reused), then store ----
    __syncthreads();   // all A reads done before panes overwrite the region
    float* pane = (float*)smem;              // 4 panes of [32][33] f32
    const int pbase = w * (32 * 33);
    if (g == 1) {
#pragma unroll
        for (int rg = 0; rg < 2; ++rg)
#pragma unroll
            for (int n = 0; n < 2; ++n)
#pragma unroll
                for (int q = 0; q < 4; ++q) {
                    int row = rg * 16 + ksub * 4 + q;
                    pane[pbase + row * 33 + n * 16 + r0] = acc[rg][n][q];
                }
    }
    __syncthreads();
    if (g == 0) {
        float s = scale[0];
#pragma unroll
        for (int rg = 0; rg < 2; ++rg)
#pragma unroll
            for (int n = 0; n < 2; ++n)
#pragma unroll
                for (int q = 0; q < 4; ++q) {
                    int row = rg * 16 + ksub * 4 + q;
                    float v = acc[rg][n][q] + pane[pbase + row * 33 + n * 16 + r0];
                    out[(size_t)(m0 + row) * OUT_DIM + w * 32 + n * 16 + r0] = v * s;
                }
    }
}

// ---------------------------------------------------------------------------
// Fallback: fully fused f32, correct but slow (only if B % 32 != 0).
// ---------------------------------------------------------------------------
__global__ void k_naive(const float* __restrict__ x, const float* __restrict__ grid,
                        const float* __restrict__ C, const float* __restrict__ W,
                        const float* __restrict__ scale, float* __restrict__ out) {
    __shared__ float sS[128];
    __shared__ float sB[128][8];
    int b = blockIdx.x, t = threadIdx.x;   // 128 threads
    float xv = x[(size_t)b * IN_DIM + t];
    float g0 = grid[0];
    float inv_h = 1.f / (grid[4] - grid[3]);
    sS[t] = xv / (1.f + __expf(-xv));
    int j; float w0, w1, w2, w3;
    basis_weights(xv, g0, inv_h, j, w0, w1, w2, w3);
    bool inrange = (j >= 0) && (j < 11);
#pragma unroll
    for (int m = 0; m < 8; ++m) {
        int k2 = m - (j - 3);
        float val = 0.f;
        if (inrange && k2 >= 0 && k2 < 4)
            val = (k2 == 0) ? w0 : (k2 == 1) ? w1 : (k2 == 2) ? w2 : w3;
        sB[t][m] = val;
    }
    __syncthreads();
    float acc = 0.f;
    for (int i = 0; i < IN_DIM; ++i) {
        acc += sS[i] * W[(size_t)i * OUT_DIM + t];
        const float* c = C + ((size_t)i * OUT_DIM + t) * NB;
#pragma unroll
        for (int m = 0; m < 8; ++m) acc += sB[i][m] * c[m];
    }
    out[(size_t)b * OUT_DIM + t] = acc * scale[0];
}

// ---------------------------------------------------------------------------
extern "C" void kernel_launch(void* const* d_in, const int* in_sizes, int n_in,
                              void* d_out, int out_size, void* d_ws, size_t ws_size,
                              hipStream_t stream) {
    const float* x     = (const float*)d_in[0];
    const float* grid  = (const float*)d_in[1];
    const float* C     = (const float*)d_in[2];
    const float* W     = (const float*)d_in[3];
    const float* scale = (const float*)d_in[4];
    float* out = (float*)d_out;

    int B = in_sizes[0] / IN_DIM;   // 8192

    if ((B % BM) == 0) {
        k_kan<<<B / BM, 512, 0, stream>>>(x, grid, C, W, scale, out);
    } else {
        k_naive<<<B, 128, 0, stream>>>(x, grid, C, W, scale, out);
    }
}